// Round 4
// baseline (168.578 us; speedup 1.0000x reference)
//
#include <hip/hip_runtime.h>

// Problem constants
#define NB 2        // batch
#define NPTS 1024   // points per cloud
#define NGEN 65536  // G * D_IN generated points per batch

// ws layout (float offsets), all 16B-aligned where accessed as float4.
#define OFF_GW    0        // 8192
#define OFF_H1P   8192     // 24576 (24 k-chunks x 2 b x 512 j)
#define OFF_ZW    32768    // 256 (pad to 512)
#define OFF_S4    33280    // 8192
#define OFF_Y4    41472    // 524288
#define OFF_WT4   565760   // 1572864 (3*128*1024 float4)
#define OFF_MPART 2138624  // 131072
// total 2269696 floats = 9.08 MB

// ---------------- KA: init + S4 pack + gw + Wd3 transpose + enc1 ----------------
__global__ __launch_bounds__(256) void kA_init(
    const float* __restrict__ x, const float* __restrict__ grid,
    const float* __restrict__ Wd1, const float* __restrict__ Wd3,
    const float* __restrict__ We1,
    float* __restrict__ gw, float* __restrict__ S4,
    float4* __restrict__ Wt4, float* __restrict__ h1part) {
  if (blockIdx.x < 64) {
    int t = blockIdx.x * 256 + threadIdx.x;
    if (t < 8192) {
      int g = t >> 7, j = t & 127;
      float a = grid[g * 3 + 0] * Wd1[64 * 128 + j]
              + grid[g * 3 + 1] * Wd1[65 * 128 + j]
              + grid[g * 3 + 2] * Wd1[66 * 128 + j];
      gw[t] = a;
    } else if (t < 10240) {
      int p = t - 8192;
      const float* xp = x + p * 3;
      float s0 = xp[0], s1 = xp[1], s2 = xp[2];
      ((float4*)S4)[p] = make_float4(s0, s1, s2, s0 * s0 + s1 * s1 + s2 * s2);
    }
  } else if (blockIdx.x < 1600) {
    int tid = (blockIdx.x - 64) * 256 + threadIdx.x;  // 0..393215
    int p  = tid & 1023;
    int k4 = (tid >> 10) & 127;
    int c  = tid >> 17;                               // 0..2
    const float* W = Wd3 + (k4 * 4) * 3072 + p * 3 + c;
    float w0 = W[0], w1 = W[3072], w2 = W[2 * 3072], w3 = W[3 * 3072];
    Wt4[(c * 128 + k4) * 1024 + p] = make_float4(w0, w1, w2, w3);
  } else {
    // enc1: 96 blocks = 24 kc x 2 jh x 2 b; 256 threads each.
    int idx = blockIdx.x - 1600;                      // 0..95
    int kc = idx % 24;
    int rest = idx / 24;                              // 0..3
    int jh = rest & 1;
    int b  = rest >> 1;
    int j = jh * 256 + threadIdx.x;
    const float* xb = x + b * 3072 + kc * 128;        // uniform -> s_load
    const float* W  = We1 + (kc * 128) * 512 + j;
    float acc = 0.f;
#pragma unroll 8
    for (int k = 0; k < 128; ++k) acc += xb[k] * W[k * 512];
    h1part[kc * 1024 + b * 512 + j] = acc;            // non-atomic partial
  }
}

// ---------------- KB: encoder tail (h1->h2->z->zw), wide k-split ----------------
// 2 blocks (one per batch) x 1024 threads. Short K-slices per phase keep the
// load-latency chain minimal; LDS partial-reduce between phases.
__global__ __launch_bounds__(1024) void kB_enc(
    const float* __restrict__ h1part, const float* __restrict__ be1,
    const float* __restrict__ We2, const float* __restrict__ be2,
    const float* __restrict__ We3, const float* __restrict__ be3,
    const float* __restrict__ Wd1, const float* __restrict__ bd1,
    float* __restrict__ zw, float* __restrict__ out) {
  __shared__ float h1l[512];
  __shared__ float h2p[1024];
  __shared__ float h2l[128];
  __shared__ float zp[1024];
  __shared__ float zl[64];
  __shared__ float wp[1024];
  int b = blockIdx.x;
  int t = threadIdx.x;
  if (b == 0 && t == 0) out[0] = 0.f;
  // h1[k] = relu(be1[k] + sum_kc h1part[kc][b][k]); one k per thread (t<512).
  if (t < 512) {
    float a = be1[t];
#pragma unroll
    for (int kc = 0; kc < 24; ++kc) a += h1part[kc * 1024 + b * 512 + t];
    h1l[t] = fmaxf(a, 0.f);
  }
  __syncthreads();
  // h2 partials: thread (q<8, j<128) does K-slice of 64.
  {
    int q = t >> 7, j = t & 127;
    const float* W = We2 + (q * 64) * 128 + j;
    const float* h = h1l + q * 64;
    float a = 0.f;
#pragma unroll 16
    for (int kk = 0; kk < 64; ++kk) a += h[kk] * W[kk * 128];
    h2p[t] = a;
  }
  __syncthreads();
  if (t < 128) {
    float a = be2[t];
#pragma unroll
    for (int q = 0; q < 8; ++q) a += h2p[q * 128 + t];
    h2l[t] = fmaxf(a, 0.f);
  }
  __syncthreads();
  // z partials: thread (q<16, j<64) does K-slice of 8.
  {
    int q = t >> 6, j = t & 63;
    float a = 0.f;
#pragma unroll
    for (int kk = 0; kk < 8; ++kk) {
      int k = q * 8 + kk;
      a += h2l[k] * We3[k * 64 + j];
    }
    zp[t] = a;
  }
  __syncthreads();
  if (t < 64) {
    float a = be3[t];
#pragma unroll
    for (int q = 0; q < 16; ++q) a += zp[q * 64 + t];
    zl[t] = fmaxf(a, 0.f);
  }
  __syncthreads();
  // zw partials: thread (q<8, j<128) does K-slice of 8 over Wd1 rows 0..63.
  {
    int q = t >> 7, j = t & 127;
    float a = 0.f;
#pragma unroll
    for (int kk = 0; kk < 8; ++kk) {
      int k = q * 8 + kk;
      a += zl[k] * Wd1[k * 128 + j];
    }
    wp[t] = a;
  }
  __syncthreads();
  if (t < 128) {
    float a = bd1[t];
#pragma unroll
    for (int q = 0; q < 8; ++q) a += wp[q * 128 + t];
    zw[b * 128 + t] = a;
  }
}

// ---------------- KC: dec2 + dec3 + tanh + (-2y,|y|^2) pack ----------------
// 256 blocks; XCD-aware remap: blocks with the same pg (which share the same
// 384 KB Wt4 slice) are pinned to one XCD (round-robin dispatch assumption),
// so per-XCD L2 holds its 2 slices (768 KB) and Wt4 re-reads become L2 hits.
__global__ __launch_bounds__(512) void kC_dec23_y4(
    const float* __restrict__ zw, const float* __restrict__ gw,
    const float* __restrict__ Wd2, const float* __restrict__ bd2,
    const float4* __restrict__ Wt4, const float* __restrict__ bd3,
    float4* __restrict__ Y4) {
  __shared__ float4 a_lds[8 * 128];        // 8 rows x 512 k = 16 KB
  __shared__ float part[8 * 3 * 8 * 64];   // [r][c][w][lane] = 48 KB
  __shared__ float d1l[8 * 128];           // 4 KB
  int xcd = blockIdx.x & 7;
  int idx = blockIdx.x >> 3;               // 0..31
  int pg = xcd * 2 + (idx & 1);            // same-pg blocks -> same XCD
  int rt = idx >> 1;                       // 0..15
  int t = threadIdx.x;
  // Phase A: d1 for rows rt*8..rt*8+7
#pragma unroll
  for (int i = 0; i < 2; ++i) {
    int idx2 = i * 512 + t;
    int r = idx2 >> 7, kk = idx2 & 127;
    int row = rt * 8 + r, b = row >> 6, g = row & 63;
    d1l[idx2] = fmaxf(zw[b * 128 + kk] + gw[g * 128 + kk], 0.f);
  }
  __syncthreads();
  // Phase B: dec2 -> a_lds rows (thread = output column j)
  {
    float* a_f = (float*)a_lds;
    int j = t;
    float bj = bd2[j];
    float acc[8];
#pragma unroll
    for (int r = 0; r < 8; ++r) acc[r] = bj;
#pragma unroll 8
    for (int k = 0; k < 128; ++k) {
      float wv = Wd2[k * 512 + j];
#pragma unroll
      for (int r = 0; r < 8; ++r) acc[r] += d1l[r * 128 + k] * wv;
    }
#pragma unroll
    for (int r = 0; r < 8; ++r) a_f[r * 512 + j] = fmaxf(acc[r], 0.f);
  }
  __syncthreads();
  // Phase C: dec3 (wave w owns k4 range [16w,16w+16) for ALL 8 rows)
  int lane = t & 63, w = t >> 6;           // w = 0..7
  int p = pg * 64 + lane;
  const float4* wp0 = Wt4 + p;             // c=0
  const float4* wp1 = Wt4 + 131072 + p;    // c=1
  const float4* wp2 = Wt4 + 262144 + p;    // c=2
  float acc[8][3];
#pragma unroll
  for (int r = 0; r < 8; ++r)
#pragma unroll
    for (int c = 0; c < 3; ++c) acc[r][c] = 0.f;
  int kbase = w * 16;
#pragma unroll 4
  for (int i = 0; i < 16; ++i) {
    int k4 = kbase + i;
    float4 w0 = wp0[k4 * 1024];
    float4 w1 = wp1[k4 * 1024];
    float4 w2 = wp2[k4 * 1024];
#pragma unroll
    for (int r = 0; r < 8; ++r) {
      float4 A = a_lds[r * 128 + k4];      // wave-uniform broadcast
      acc[r][0] += A.x * w0.x + A.y * w0.y + A.z * w0.z + A.w * w0.w;
      acc[r][1] += A.x * w1.x + A.y * w1.y + A.z * w1.z + A.w * w1.w;
      acc[r][2] += A.x * w2.x + A.y * w2.y + A.z * w2.z + A.w * w2.w;
    }
  }
#pragma unroll
  for (int r = 0; r < 8; ++r)
#pragma unroll
    for (int c = 0; c < 3; ++c)
      part[((r * 3 + c) * 8 + w) * 64 + lane] = acc[r][c];
  __syncthreads();
  // combine: thread (w,lane) -> output row w, col p
  {
    int r = w;
    float s0 = 0.f, s1 = 0.f, s2 = 0.f;
#pragma unroll
    for (int ww = 0; ww < 8; ++ww) {
      s0 += part[((r * 3 + 0) * 8 + ww) * 64 + lane];
      s1 += part[((r * 3 + 1) * 8 + ww) * 64 + lane];
      s2 += part[((r * 3 + 2) * 8 + ww) * 64 + lane];
    }
    float b0 = bd3[p * 3], b1 = bd3[p * 3 + 1], b2 = bd3[p * 3 + 2];
    float y0 = tanhf(s0 + b0), y1 = tanhf(s1 + b1), y2 = tanhf(s2 + b2);
    int row = rt * 8 + r;
    Y4[row * 1024 + p] = make_float4(-2.f * y0, -2.f * y1, -2.f * y2,
                                     y0 * y0 + y1 * y1 + y2 * y2);
  }
}

// ---------------- KD: merged chamfer, 4 insts/pair (verified scalar loop) --------
// blocks 0..255: dir1 (sum_n min_m), blocks 256..511: dir2 partial mins.
// Exactly 2048 waves = 2 waves/SIMD.
__global__ __launch_bounds__(256) void kD_chamfer(
    const float4* __restrict__ Y4, const float4* __restrict__ S4,
    float* __restrict__ mpart, float* __restrict__ out) {
  __shared__ float4 c_lds[1024];           // 16 KB inner cloud
  int t = threadIdx.x;
  if (blockIdx.x < 256) {
    // ---- dir1: resident my = (-2y, |y|^2); LDS = S (plain, |s|^2) ----
    int b = blockIdx.x >> 7, nt = blockIdx.x & 127;
    {
      const float4* src = S4 + b * 1024;
#pragma unroll
      for (int i = 0; i < 4; ++i) c_lds[i * 256 + t] = src[i * 256 + t];
    }
    float4 my0 = Y4[b * 65536 + nt * 512 + t];
    float4 my1 = Y4[b * 65536 + nt * 512 + 256 + t];
    __syncthreads();
    float mn0 = __builtin_inff(), mn1 = mn0;
#pragma unroll 8
    for (int m = 0; m < 1024; ++m) {
      float4 s = c_lds[m];                 // block-uniform broadcast
      float d0 = __builtin_fmaf(s.x, my0.x,
                 __builtin_fmaf(s.y, my0.y,
                 __builtin_fmaf(s.z, my0.z, s.w)));
      float d1 = __builtin_fmaf(s.x, my1.x,
                 __builtin_fmaf(s.y, my1.y,
                 __builtin_fmaf(s.z, my1.z, s.w)));
      mn0 = fminf(mn0, d0);
      mn1 = fminf(mn1, d1);
    }
    float v = (mn0 + my0.w) + (mn1 + my1.w);
#pragma unroll
    for (int off = 32; off > 0; off >>= 1) v += __shfl_down(v, off);
    __shared__ float bsum[4];
    int lane = t & 63, w = t >> 6;
    if (lane == 0) bsum[w] = v;
    __syncthreads();
    if (t == 0) atomicAdd(out, bsum[0] + bsum[1] + bsum[2] + bsum[3]);
  } else {
    // ---- dir2: resident s (plain); LDS = Y' = (-2y, |y|^2) ----
    int blk = blockIdx.x - 256;            // 0..255
    int b   = blk >> 7;
    int mg  = (blk >> 6) & 1;
    int nch = blk & 63;
    {
      const float4* src = Y4 + b * 65536 + nch * 1024;
#pragma unroll
      for (int i = 0; i < 4; ++i) c_lds[i * 256 + t] = src[i * 256 + t];
    }
    float4 s0 = S4[b * 1024 + mg * 512 + t];
    float4 s1 = S4[b * 1024 + mg * 512 + 256 + t];
    __syncthreads();
    float mn0 = __builtin_inff(), mn1 = mn0;
#pragma unroll 8
    for (int n = 0; n < 1024; ++n) {
      float4 y = c_lds[n];
      float d0 = __builtin_fmaf(y.x, s0.x,
                 __builtin_fmaf(y.y, s0.y,
                 __builtin_fmaf(y.z, s0.z, y.w)));
      float d1 = __builtin_fmaf(y.x, s1.x,
                 __builtin_fmaf(y.y, s1.y,
                 __builtin_fmaf(y.z, s1.z, y.w)));
      mn0 = fminf(mn0, d0);
      mn1 = fminf(mn1, d1);
    }
    int base = (nch * 2 + b) * 1024 + mg * 512;
    mpart[base + t]       = mn0 + s0.w;
    mpart[base + 256 + t] = mn1 + s1.w;
  }
}

// ---------------- KE: dir2 final reduce ----------------
__global__ __launch_bounds__(256) void kE_dir2_reduce(
    const float* __restrict__ mpart, float* __restrict__ out) {
  int gid = blockIdx.x * 256 + threadIdx.x;   // 0..2047
  int b = gid >> 10, m = gid & 1023;
  float v = __builtin_inff();
#pragma unroll 8
  for (int ch = 0; ch < 64; ++ch)
    v = fminf(v, mpart[(ch * 2 + b) * 1024 + m]);  // coalesced over m
#pragma unroll
  for (int off = 32; off > 0; off >>= 1) v += __shfl_down(v, off);
  __shared__ float bsum[4];
  int lane = threadIdx.x & 63, w = threadIdx.x >> 6;
  if (lane == 0) bsum[w] = v;
  __syncthreads();
  if (threadIdx.x == 0) atomicAdd(out, bsum[0] + bsum[1] + bsum[2] + bsum[3]);
}

extern "C" void kernel_launch(void* const* d_in, const int* in_sizes, int n_in,
                              void* d_out, int out_size, void* d_ws, size_t ws_size,
                              hipStream_t stream) {
  const float* x   = (const float*)d_in[0];
  const float* grd = (const float*)d_in[1];
  const float* We1 = (const float*)d_in[2];
  const float* be1 = (const float*)d_in[3];
  const float* We2 = (const float*)d_in[4];
  const float* be2 = (const float*)d_in[5];
  const float* We3 = (const float*)d_in[6];
  const float* be3 = (const float*)d_in[7];
  const float* Wd1 = (const float*)d_in[8];
  const float* bd1 = (const float*)d_in[9];
  const float* Wd2 = (const float*)d_in[10];
  const float* bd2 = (const float*)d_in[11];
  const float* Wd3 = (const float*)d_in[12];
  const float* bd3 = (const float*)d_in[13];
  float* ws = (float*)d_ws;
  float* out = (float*)d_out;

  float* gw     = ws + OFF_GW;
  float* h1part = ws + OFF_H1P;
  float* zw     = ws + OFF_ZW;
  float* S4     = ws + OFF_S4;
  float* Y4     = ws + OFF_Y4;
  float4* Wt4   = (float4*)(ws + OFF_WT4);
  float* mpart  = ws + OFF_MPART;

  hipLaunchKernelGGL(kA_init, dim3(1696), dim3(256), 0, stream,
                     x, grd, Wd1, Wd3, We1, gw, S4, Wt4, h1part);
  hipLaunchKernelGGL(kB_enc, dim3(2), dim3(1024), 0, stream,
                     h1part, be1, We2, be2, We3, be3, Wd1, bd1, zw, out);
  hipLaunchKernelGGL(kC_dec23_y4, dim3(256), dim3(512), 0, stream,
                     zw, gw, Wd2, bd2, Wt4, bd3, (float4*)Y4);
  hipLaunchKernelGGL(kD_chamfer, dim3(512), dim3(256), 0, stream,
                     (const float4*)Y4, (const float4*)S4, mpart, out);
  hipLaunchKernelGGL(kE_dir2_reduce, dim3(8), dim3(256), 0, stream,
                     mpart, out);
}

// Round 5
// 165.387 us; speedup vs baseline: 1.0193x; 1.0193x over previous
//
#include <hip/hip_runtime.h>

// Problem constants
#define NB 2        // batch
#define NPTS 1024   // points per cloud
#define NGEN 65536  // G * D_IN generated points per batch

typedef float f32x2 __attribute__((ext_vector_type(2)));

// ws layout (float offsets), all 16B-aligned where accessed as float4.
#define OFF_GW    0        // 8192
#define OFF_H1P   8192     // 24576 (24 k-chunks x 2 b x 512 j)
#define OFF_ZW    32768    // 256 (pad to 512)
#define OFF_S4    33280    // 8192
#define OFF_Y4    41472    // 524288
#define OFF_WT4   565760   // 1572864 (3*128*1024 float4)
#define OFF_MPART 2138624  // 131072
// total 2269696 floats = 9.08 MB

// ---------------- KA: init + S4 pack + gw + Wd3 transpose + enc1 ----------------
__global__ __launch_bounds__(256) void kA_init(
    const float* __restrict__ x, const float* __restrict__ grid,
    const float* __restrict__ Wd1, const float* __restrict__ Wd3,
    const float* __restrict__ We1,
    float* __restrict__ gw, float* __restrict__ S4,
    float4* __restrict__ Wt4, float* __restrict__ h1part) {
  if (blockIdx.x < 64) {
    int t = blockIdx.x * 256 + threadIdx.x;
    if (t < 8192) {
      int g = t >> 7, j = t & 127;
      float a = grid[g * 3 + 0] * Wd1[64 * 128 + j]
              + grid[g * 3 + 1] * Wd1[65 * 128 + j]
              + grid[g * 3 + 2] * Wd1[66 * 128 + j];
      gw[t] = a;
    } else if (t < 10240) {
      int p = t - 8192;
      const float* xp = x + p * 3;
      float s0 = xp[0], s1 = xp[1], s2 = xp[2];
      ((float4*)S4)[p] = make_float4(s0, s1, s2, s0 * s0 + s1 * s1 + s2 * s2);
    }
  } else if (blockIdx.x < 1600) {
    int tid = (blockIdx.x - 64) * 256 + threadIdx.x;  // 0..393215
    int p  = tid & 1023;
    int k4 = (tid >> 10) & 127;
    int c  = tid >> 17;                               // 0..2
    const float* W = Wd3 + (k4 * 4) * 3072 + p * 3 + c;
    float w0 = W[0], w1 = W[3072], w2 = W[2 * 3072], w3 = W[3 * 3072];
    Wt4[(c * 128 + k4) * 1024 + p] = make_float4(w0, w1, w2, w3);
  } else {
    // enc1: 96 blocks = 24 kc x 2 jh x 2 b; 256 threads each.
    int idx = blockIdx.x - 1600;                      // 0..95
    int kc = idx % 24;
    int rest = idx / 24;                              // 0..3
    int jh = rest & 1;
    int b  = rest >> 1;
    int j = jh * 256 + threadIdx.x;
    const float* xb = x + b * 3072 + kc * 128;        // uniform -> s_load
    const float* W  = We1 + (kc * 128) * 512 + j;
    float acc = 0.f;
#pragma unroll 8
    for (int k = 0; k < 128; ++k) acc += xb[k] * W[k * 512];
    h1part[kc * 1024 + b * 512 + j] = acc;            // non-atomic partial
  }
}

// ---------------- KB: encoder tail (h1->h2->z->zw), k-split (R2-verified) --------
// 2 blocks (one per batch) x 512 threads. Every phase splits K across q
// sub-chunks so all global loads issue concurrently; LDS partial-reduce.
// Also zeroes out[0].
__global__ __launch_bounds__(512) void kB_enc(
    const float* __restrict__ h1part, const float* __restrict__ be1,
    const float* __restrict__ We2, const float* __restrict__ be2,
    const float* __restrict__ We3, const float* __restrict__ be3,
    const float* __restrict__ Wd1, const float* __restrict__ bd1,
    float* __restrict__ zw, float* __restrict__ out) {
  __shared__ float h1l[512];
  __shared__ float h2p[512];
  __shared__ float h2l[128];
  __shared__ float zp[512];
  __shared__ float zl[64];
  __shared__ float wp[512];
  int b = blockIdx.x;
  int t = threadIdx.x;
  if (b == 0 && t == 0) out[0] = 0.f;
  // h1[k] = relu(be1[k] + sum_kc h1part[kc][b][k]); one k per thread.
  {
    float a = be1[t];
#pragma unroll
    for (int kc = 0; kc < 24; ++kc) a += h1part[kc * 1024 + b * 512 + t];
    h1l[t] = fmaxf(a, 0.f);
  }
  __syncthreads();
  // h2 partials: thread (q<4, j<128) does K-slice [128q,128q+128).
  {
    int q = t >> 7, j = t & 127;
    const float* W = We2 + (q * 128) * 128 + j;
    const float* h = h1l + q * 128;
    float a = 0.f;
#pragma unroll 16
    for (int k = 0; k < 128; ++k) a += h[k] * W[k * 128];
    h2p[t] = a;
  }
  __syncthreads();
  if (t < 128)
    h2l[t] = fmaxf(h2p[t] + h2p[128 + t] + h2p[256 + t] + h2p[384 + t]
                   + be2[t], 0.f);
  __syncthreads();
  // z partials: thread (q<8, j<64) does K-slice of 16.
  {
    int q = t >> 6, j = t & 63;
    float a = 0.f;
#pragma unroll
    for (int kk = 0; kk < 16; ++kk) {
      int k = q * 16 + kk;
      a += h2l[k] * We3[k * 64 + j];
    }
    zp[t] = a;
  }
  __syncthreads();
  if (t < 64) {
    float a = be3[t];
#pragma unroll
    for (int q = 0; q < 8; ++q) a += zp[q * 64 + t];
    zl[t] = fmaxf(a, 0.f);
  }
  __syncthreads();
  // zw partials: thread (q<4, j<128) does K-slice of 16 over Wd1 rows 0..63.
  {
    int q = t >> 7, j = t & 127;
    float a = 0.f;
#pragma unroll
    for (int kk = 0; kk < 16; ++kk) {
      int k = q * 16 + kk;
      a += zl[k] * Wd1[k * 128 + j];
    }
    wp[t] = a;
  }
  __syncthreads();
  if (t < 128)
    zw[b * 128 + t] = wp[t] + wp[128 + t] + wp[256 + t] + wp[384 + t]
                      + bd1[t];
}

// ---------------- KC: dec2 + dec3 + tanh + (-2y,|y|^2) pack ----------------
// 256 blocks = rt(16) x pg(16) (R2 mapping); 512 threads = 8 waves.
// Phase A: d1 = relu(zw+gw), stored [k][r] so phase B reads 2 b128 / k.
// Phase B: dec2 -> a_lds; packed f32x2 accumulators (4 pk_fma per k).
// Phase C: dec3 k-split: wave w owns k4 range [16w,16w+16) for ALL 8 rows.
__global__ __launch_bounds__(512) void kC_dec23_y4(
    const float* __restrict__ zw, const float* __restrict__ gw,
    const float* __restrict__ Wd2, const float* __restrict__ bd2,
    const float4* __restrict__ Wt4, const float* __restrict__ bd3,
    float4* __restrict__ Y4) {
  __shared__ float4 a_lds[8 * 128];        // 8 rows x 512 k = 16 KB
  __shared__ float part[8 * 3 * 8 * 64];   // [r][c][w][lane] = 48 KB
  __shared__ float d1l[128 * 8];           // [k][r], 4 KB
  int rt = blockIdx.x >> 4;
  int pg = blockIdx.x & 15;
  int t = threadIdx.x;
  // Phase A: d1 for rows rt*8..rt*8+7, stored d1l[kk*8 + r]
#pragma unroll
  for (int i = 0; i < 2; ++i) {
    int idx2 = i * 512 + t;
    int r = idx2 >> 7, kk = idx2 & 127;
    int row = rt * 8 + r, b = row >> 6, g = row & 63;
    d1l[kk * 8 + r] = fmaxf(zw[b * 128 + kk] + gw[g * 128 + kk], 0.f);
  }
  __syncthreads();
  // Phase B: dec2 -> a_lds rows (thread = output column j); packed pairs.
  {
    float* a_f = (float*)a_lds;
    int j = t;
    float bj = bd2[j];
    f32x2 acc01 = {bj, bj}, acc23 = {bj, bj};
    f32x2 acc45 = {bj, bj}, acc67 = {bj, bj};
#pragma unroll 8
    for (int k = 0; k < 128; ++k) {
      float wv = Wd2[k * 512 + j];
      f32x2 wv2 = {wv, wv};
      float4 lo = *(const float4*)(d1l + k * 8);      // rows 0..3 (broadcast)
      float4 hi = *(const float4*)(d1l + k * 8 + 4);  // rows 4..7
      f32x2 d01 = {lo.x, lo.y}, d23 = {lo.z, lo.w};
      f32x2 d45 = {hi.x, hi.y}, d67 = {hi.z, hi.w};
      acc01 = __builtin_elementwise_fma(d01, wv2, acc01);
      acc23 = __builtin_elementwise_fma(d23, wv2, acc23);
      acc45 = __builtin_elementwise_fma(d45, wv2, acc45);
      acc67 = __builtin_elementwise_fma(d67, wv2, acc67);
    }
    a_f[0 * 512 + j] = fmaxf(acc01.x, 0.f);
    a_f[1 * 512 + j] = fmaxf(acc01.y, 0.f);
    a_f[2 * 512 + j] = fmaxf(acc23.x, 0.f);
    a_f[3 * 512 + j] = fmaxf(acc23.y, 0.f);
    a_f[4 * 512 + j] = fmaxf(acc45.x, 0.f);
    a_f[5 * 512 + j] = fmaxf(acc45.y, 0.f);
    a_f[6 * 512 + j] = fmaxf(acc67.x, 0.f);
    a_f[7 * 512 + j] = fmaxf(acc67.y, 0.f);
  }
  __syncthreads();
  // Phase C: dec3 (wave w owns k4 range [16w,16w+16) for ALL 8 rows)
  int lane = t & 63, w = t >> 6;           // w = 0..7
  int p = pg * 64 + lane;
  const float4* wp0 = Wt4 + p;             // c=0
  const float4* wp1 = Wt4 + 131072 + p;    // c=1
  const float4* wp2 = Wt4 + 262144 + p;    // c=2
  float acc[8][3];
#pragma unroll
  for (int r = 0; r < 8; ++r)
#pragma unroll
    for (int c = 0; c < 3; ++c) acc[r][c] = 0.f;
  int kbase = w * 16;
#pragma unroll 4
  for (int i = 0; i < 16; ++i) {
    int k4 = kbase + i;
    float4 w0 = wp0[k4 * 1024];
    float4 w1 = wp1[k4 * 1024];
    float4 w2 = wp2[k4 * 1024];
#pragma unroll
    for (int r = 0; r < 8; ++r) {
      float4 A = a_lds[r * 128 + k4];      // wave-uniform broadcast
      acc[r][0] += A.x * w0.x + A.y * w0.y + A.z * w0.z + A.w * w0.w;
      acc[r][1] += A.x * w1.x + A.y * w1.y + A.z * w1.z + A.w * w1.w;
      acc[r][2] += A.x * w2.x + A.y * w2.y + A.z * w2.z + A.w * w2.w;
    }
  }
#pragma unroll
  for (int r = 0; r < 8; ++r)
#pragma unroll
    for (int c = 0; c < 3; ++c)
      part[((r * 3 + c) * 8 + w) * 64 + lane] = acc[r][c];
  __syncthreads();
  // combine: thread (w,lane) -> output row w, col p
  {
    int r = w;
    float s0 = 0.f, s1 = 0.f, s2 = 0.f;
#pragma unroll
    for (int ww = 0; ww < 8; ++ww) {
      s0 += part[((r * 3 + 0) * 8 + ww) * 64 + lane];
      s1 += part[((r * 3 + 1) * 8 + ww) * 64 + lane];
      s2 += part[((r * 3 + 2) * 8 + ww) * 64 + lane];
    }
    float b0 = bd3[p * 3], b1 = bd3[p * 3 + 1], b2 = bd3[p * 3 + 2];
    float y0 = tanhf(s0 + b0), y1 = tanhf(s1 + b1), y2 = tanhf(s2 + b2);
    int row = rt * 8 + r;
    Y4[row * 1024 + p] = make_float4(-2.f * y0, -2.f * y1, -2.f * y2,
                                     y0 * y0 + y1 * y1 + y2 * y2);
  }
}

// ---------------- KD: merged chamfer, packed f32x2 hot loop ----------------
// blocks 0..255: dir1 (sum_n min_m), blocks 256..511: dir2 partial mins.
// Pair of distances via __builtin_elementwise_fma on float2 (compiler may
// select v_pk_fma_f32): 3 fma-ops + 2 min per 2 pairs. FMA nesting order
// (z, then y, then x) matches the verified scalar loop -> identical results.
__global__ __launch_bounds__(256) void kD_chamfer(
    const float4* __restrict__ Y4, const float4* __restrict__ S4,
    float* __restrict__ mpart, float* __restrict__ out) {
  __shared__ float4 c_lds[1024];           // 16 KB inner cloud
  int t = threadIdx.x;
  if (blockIdx.x < 256) {
    // ---- dir1: resident my = (-2y, |y|^2); LDS = S (plain, |s|^2) ----
    int b = blockIdx.x >> 7, nt = blockIdx.x & 127;
    {
      const float4* src = S4 + b * 1024;
#pragma unroll
      for (int i = 0; i < 4; ++i) c_lds[i * 256 + t] = src[i * 256 + t];
    }
    float4 my0 = Y4[b * 65536 + nt * 512 + t];
    float4 my1 = Y4[b * 65536 + nt * 512 + 256 + t];
    f32x2 mx2 = {my0.x, my1.x};
    f32x2 my2 = {my0.y, my1.y};
    f32x2 mz2 = {my0.z, my1.z};
    __syncthreads();
    float mn0 = __builtin_inff(), mn1 = mn0;
#pragma unroll 8
    for (int m = 0; m < 1024; ++m) {
      float4 s = c_lds[m];                 // block-uniform broadcast
      f32x2 sx2 = {s.x, s.x}, sy2 = {s.y, s.y};
      f32x2 sz2 = {s.z, s.z}, sw2 = {s.w, s.w};
      f32x2 d = __builtin_elementwise_fma(sz2, mz2, sw2);
      d = __builtin_elementwise_fma(sy2, my2, d);
      d = __builtin_elementwise_fma(sx2, mx2, d);
      mn0 = fminf(mn0, d.x);
      mn1 = fminf(mn1, d.y);
    }
    float v = (mn0 + my0.w) + (mn1 + my1.w);
#pragma unroll
    for (int off = 32; off > 0; off >>= 1) v += __shfl_down(v, off);
    __shared__ float bsum[4];
    int lane = t & 63, w = t >> 6;
    if (lane == 0) bsum[w] = v;
    __syncthreads();
    if (t == 0) atomicAdd(out, bsum[0] + bsum[1] + bsum[2] + bsum[3]);
  } else {
    // ---- dir2: resident s (plain); LDS = Y' = (-2y, |y|^2) ----
    int blk = blockIdx.x - 256;            // 0..255
    int b   = blk >> 7;
    int mg  = (blk >> 6) & 1;
    int nch = blk & 63;
    {
      const float4* src = Y4 + b * 65536 + nch * 1024;
#pragma unroll
      for (int i = 0; i < 4; ++i) c_lds[i * 256 + t] = src[i * 256 + t];
    }
    float4 s0 = S4[b * 1024 + mg * 512 + t];
    float4 s1 = S4[b * 1024 + mg * 512 + 256 + t];
    f32x2 sx2 = {s0.x, s1.x};
    f32x2 sy2 = {s0.y, s1.y};
    f32x2 sz2 = {s0.z, s1.z};
    __syncthreads();
    float mn0 = __builtin_inff(), mn1 = mn0;
#pragma unroll 8
    for (int n = 0; n < 1024; ++n) {
      float4 y = c_lds[n];
      f32x2 yx2 = {y.x, y.x}, yy2 = {y.y, y.y};
      f32x2 yz2 = {y.z, y.z}, yw2 = {y.w, y.w};
      f32x2 d = __builtin_elementwise_fma(yz2, sz2, yw2);
      d = __builtin_elementwise_fma(yy2, sy2, d);
      d = __builtin_elementwise_fma(yx2, sx2, d);
      mn0 = fminf(mn0, d.x);
      mn1 = fminf(mn1, d.y);
    }
    int base = (nch * 2 + b) * 1024 + mg * 512;
    mpart[base + t]       = mn0 + s0.w;
    mpart[base + 256 + t] = mn1 + s1.w;
  }
}

// ---------------- KE: dir2 final reduce ----------------
__global__ __launch_bounds__(256) void kE_dir2_reduce(
    const float* __restrict__ mpart, float* __restrict__ out) {
  int gid = blockIdx.x * 256 + threadIdx.x;   // 0..2047
  int b = gid >> 10, m = gid & 1023;
  float v = __builtin_inff();
#pragma unroll 8
  for (int ch = 0; ch < 64; ++ch)
    v = fminf(v, mpart[(ch * 2 + b) * 1024 + m]);  // coalesced over m
#pragma unroll
  for (int off = 32; off > 0; off >>= 1) v += __shfl_down(v, off);
  __shared__ float bsum[4];
  int lane = threadIdx.x & 63, w = threadIdx.x >> 6;
  if (lane == 0) bsum[w] = v;
  __syncthreads();
  if (threadIdx.x == 0) atomicAdd(out, bsum[0] + bsum[1] + bsum[2] + bsum[3]);
}

extern "C" void kernel_launch(void* const* d_in, const int* in_sizes, int n_in,
                              void* d_out, int out_size, void* d_ws, size_t ws_size,
                              hipStream_t stream) {
  const float* x   = (const float*)d_in[0];
  const float* grd = (const float*)d_in[1];
  const float* We1 = (const float*)d_in[2];
  const float* be1 = (const float*)d_in[3];
  const float* We2 = (const float*)d_in[4];
  const float* be2 = (const float*)d_in[5];
  const float* We3 = (const float*)d_in[6];
  const float* be3 = (const float*)d_in[7];
  const float* Wd1 = (const float*)d_in[8];
  const float* bd1 = (const float*)d_in[9];
  const float* Wd2 = (const float*)d_in[10];
  const float* bd2 = (const float*)d_in[11];
  const float* Wd3 = (const float*)d_in[12];
  const float* bd3 = (const float*)d_in[13];
  float* ws = (float*)d_ws;
  float* out = (float*)d_out;

  float* gw     = ws + OFF_GW;
  float* h1part = ws + OFF_H1P;
  float* zw     = ws + OFF_ZW;
  float* S4     = ws + OFF_S4;
  float* Y4     = ws + OFF_Y4;
  float4* Wt4   = (float4*)(ws + OFF_WT4);
  float* mpart  = ws + OFF_MPART;

  hipLaunchKernelGGL(kA_init, dim3(1696), dim3(256), 0, stream,
                     x, grd, Wd1, Wd3, We1, gw, S4, Wt4, h1part);
  hipLaunchKernelGGL(kB_enc, dim3(2), dim3(512), 0, stream,
                     h1part, be1, We2, be2, We3, be3, Wd1, bd1, zw, out);
  hipLaunchKernelGGL(kC_dec23_y4, dim3(256), dim3(512), 0, stream,
                     zw, gw, Wd2, bd2, Wt4, bd3, (float4*)Y4);
  hipLaunchKernelGGL(kD_chamfer, dim3(512), dim3(256), 0, stream,
                     (const float4*)Y4, (const float4*)S4, mpart, out);
  hipLaunchKernelGGL(kE_dir2_reduce, dim3(8), dim3(256), 0, stream,
                     mpart, out);
}

// Round 6
// 163.038 us; speedup vs baseline: 1.0340x; 1.0144x over previous
//
#include <hip/hip_runtime.h>

// Problem constants
#define NB 2        // batch
#define NPTS 1024   // points per cloud
#define NGEN 65536  // G * D_IN generated points per batch

typedef float f32x2 __attribute__((ext_vector_type(2)));

// ws layout (float offsets), all 16B-aligned where accessed as float4.
#define OFF_GW    0        // 8192
#define OFF_H1P   8192     // 24576 (24 k-chunks x 2 b x 512 j)
#define OFF_ZW    32768    // 256 (pad to 512)
#define OFF_S4    33280    // 8192
#define OFF_Y4    41472    // 524288
#define OFF_MPART 565760   // 131072
// total 696832 floats = 2.8 MB

// ---------------- KA: init + S4 pack + gw + enc1 (no transpose) ----------------
// blocks 0..63: gw + S4 pack; blocks 64..111: encoder L1 k-split partials,
// merged over batch (both b share each We1 load).
__global__ __launch_bounds__(256) void kA_init(
    const float* __restrict__ x, const float* __restrict__ grid,
    const float* __restrict__ Wd1, const float* __restrict__ We1,
    float* __restrict__ gw, float* __restrict__ S4,
    float* __restrict__ h1part) {
  if (blockIdx.x < 64) {
    int t = blockIdx.x * 256 + threadIdx.x;
    if (t < 8192) {
      int g = t >> 7, j = t & 127;
      float a = grid[g * 3 + 0] * Wd1[64 * 128 + j]
              + grid[g * 3 + 1] * Wd1[65 * 128 + j]
              + grid[g * 3 + 2] * Wd1[66 * 128 + j];
      gw[t] = a;
    } else if (t < 10240) {
      int p = t - 8192;
      const float* xp = x + p * 3;
      float s0 = xp[0], s1 = xp[1], s2 = xp[2];
      ((float4*)S4)[p] = make_float4(s0, s1, s2, s0 * s0 + s1 * s1 + s2 * s2);
    }
  } else {
    // enc1: 48 blocks = 24 kc x 2 jh; 256 threads each; both batches per block.
    int idx = blockIdx.x - 64;                        // 0..47
    int kc = idx % 24;
    int jh = idx / 24;                                // 0..1
    int j = jh * 256 + threadIdx.x;
    const float* xb0 = x + kc * 128;                  // uniform -> s_load
    const float* xb1 = x + 3072 + kc * 128;
    const float* W  = We1 + (kc * 128) * 512 + j;
    float acc0 = 0.f, acc1 = 0.f;
#pragma unroll 16
    for (int k = 0; k < 128; ++k) {
      float wv = W[k * 512];
      acc0 += xb0[k] * wv;
      acc1 += xb1[k] * wv;
    }
    h1part[kc * 1024 + j] = acc0;                     // b=0 partial
    h1part[kc * 1024 + 512 + j] = acc1;               // b=1 partial
  }
}

// ---------------- KB: encoder tail (h1->h2->z->zw), k-split (R2-verified) --------
// 2 blocks (one per batch) x 512 threads. Every phase splits K across q
// sub-chunks so all global loads issue concurrently; LDS partial-reduce.
// Also zeroes out[0].
__global__ __launch_bounds__(512) void kB_enc(
    const float* __restrict__ h1part, const float* __restrict__ be1,
    const float* __restrict__ We2, const float* __restrict__ be2,
    const float* __restrict__ We3, const float* __restrict__ be3,
    const float* __restrict__ Wd1, const float* __restrict__ bd1,
    float* __restrict__ zw, float* __restrict__ out) {
  __shared__ float h1l[512];
  __shared__ float h2p[512];
  __shared__ float h2l[128];
  __shared__ float zp[512];
  __shared__ float zl[64];
  __shared__ float wp[512];
  int b = blockIdx.x;
  int t = threadIdx.x;
  if (b == 0 && t == 0) out[0] = 0.f;
  // h1[k] = relu(be1[k] + sum_kc h1part[kc][b][k]); one k per thread.
  {
    float a = be1[t];
#pragma unroll
    for (int kc = 0; kc < 24; ++kc) a += h1part[kc * 1024 + b * 512 + t];
    h1l[t] = fmaxf(a, 0.f);
  }
  __syncthreads();
  // h2 partials: thread (q<4, j<128) does K-slice [128q,128q+128).
  {
    int q = t >> 7, j = t & 127;
    const float* W = We2 + (q * 128) * 128 + j;
    const float* h = h1l + q * 128;
    float a = 0.f;
#pragma unroll 16
    for (int k = 0; k < 128; ++k) a += h[k] * W[k * 128];
    h2p[t] = a;
  }
  __syncthreads();
  if (t < 128)
    h2l[t] = fmaxf(h2p[t] + h2p[128 + t] + h2p[256 + t] + h2p[384 + t]
                   + be2[t], 0.f);
  __syncthreads();
  // z partials: thread (q<8, j<64) does K-slice of 16.
  {
    int q = t >> 6, j = t & 63;
    float a = 0.f;
#pragma unroll
    for (int kk = 0; kk < 16; ++kk) {
      int k = q * 16 + kk;
      a += h2l[k] * We3[k * 64 + j];
    }
    zp[t] = a;
  }
  __syncthreads();
  if (t < 64) {
    float a = be3[t];
#pragma unroll
    for (int q = 0; q < 8; ++q) a += zp[q * 64 + t];
    zl[t] = fmaxf(a, 0.f);
  }
  __syncthreads();
  // zw partials: thread (q<4, j<128) does K-slice of 16 over Wd1 rows 0..63.
  {
    int q = t >> 7, j = t & 127;
    float a = 0.f;
#pragma unroll
    for (int kk = 0; kk < 16; ++kk) {
      int k = q * 16 + kk;
      a += zl[k] * Wd1[k * 128 + j];
    }
    wp[t] = a;
  }
  __syncthreads();
  if (t < 128)
    zw[b * 128 + t] = wp[t] + wp[128 + t] + wp[256 + t] + wp[384 + t]
                      + bd1[t];
}

// ---------------- KC: dec2 + dec3 + tanh + (-2y,|y|^2) pack ----------------
// 256 blocks = rt(16) x pg(16); 512 threads = 8 waves.
// Phase A: d1 = relu(zw+gw), stored [k][r] so phase B reads 2 b128 / k.
// Phase B: dec2 -> a_lds; packed f32x2 accumulators (4 pk_fma per k).
// Phase C: dec3 k-split reading Wd3 DIRECTLY (dwordx3 per k, 12 contiguous
// bytes/lane) — transpose kernel eliminated; same expression shape as the
// Wt4 version, bit-identical results.
__global__ __launch_bounds__(512) void kC_dec23_y4(
    const float* __restrict__ zw, const float* __restrict__ gw,
    const float* __restrict__ Wd2, const float* __restrict__ bd2,
    const float* __restrict__ Wd3, const float* __restrict__ bd3,
    float4* __restrict__ Y4) {
  __shared__ float4 a_lds[8 * 128];        // 8 rows x 512 k = 16 KB
  __shared__ float part[8 * 3 * 8 * 64];   // [r][c][w][lane] = 48 KB
  __shared__ float d1l[128 * 8];           // [k][r], 4 KB
  int rt = blockIdx.x >> 4;
  int pg = blockIdx.x & 15;
  int t = threadIdx.x;
  // Phase A: d1 for rows rt*8..rt*8+7, stored d1l[kk*8 + r]
#pragma unroll
  for (int i = 0; i < 2; ++i) {
    int idx2 = i * 512 + t;
    int r = idx2 >> 7, kk = idx2 & 127;
    int row = rt * 8 + r, b = row >> 6, g = row & 63;
    d1l[kk * 8 + r] = fmaxf(zw[b * 128 + kk] + gw[g * 128 + kk], 0.f);
  }
  __syncthreads();
  // Phase B: dec2 -> a_lds rows (thread = output column j); packed pairs.
  {
    float* a_f = (float*)a_lds;
    int j = t;
    float bj = bd2[j];
    f32x2 acc01 = {bj, bj}, acc23 = {bj, bj};
    f32x2 acc45 = {bj, bj}, acc67 = {bj, bj};
#pragma unroll 8
    for (int k = 0; k < 128; ++k) {
      float wv = Wd2[k * 512 + j];
      f32x2 wv2 = {wv, wv};
      float4 lo = *(const float4*)(d1l + k * 8);      // rows 0..3 (broadcast)
      float4 hi = *(const float4*)(d1l + k * 8 + 4);  // rows 4..7
      f32x2 d01 = {lo.x, lo.y}, d23 = {lo.z, lo.w};
      f32x2 d45 = {hi.x, hi.y}, d67 = {hi.z, hi.w};
      acc01 = __builtin_elementwise_fma(d01, wv2, acc01);
      acc23 = __builtin_elementwise_fma(d23, wv2, acc23);
      acc45 = __builtin_elementwise_fma(d45, wv2, acc45);
      acc67 = __builtin_elementwise_fma(d67, wv2, acc67);
    }
    a_f[0 * 512 + j] = fmaxf(acc01.x, 0.f);
    a_f[1 * 512 + j] = fmaxf(acc01.y, 0.f);
    a_f[2 * 512 + j] = fmaxf(acc23.x, 0.f);
    a_f[3 * 512 + j] = fmaxf(acc23.y, 0.f);
    a_f[4 * 512 + j] = fmaxf(acc45.x, 0.f);
    a_f[5 * 512 + j] = fmaxf(acc45.y, 0.f);
    a_f[6 * 512 + j] = fmaxf(acc67.x, 0.f);
    a_f[7 * 512 + j] = fmaxf(acc67.y, 0.f);
  }
  __syncthreads();
  // Phase C: dec3 (wave w owns k4 range [16w,16w+16) for ALL 8 rows)
  int lane = t & 63, w = t >> 6;           // w = 0..7
  int p = pg * 64 + lane;
  const float* wbase = Wd3 + 3 * p;        // row k at wbase + k*3072
  float acc[8][3];
#pragma unroll
  for (int r = 0; r < 8; ++r)
#pragma unroll
    for (int c = 0; c < 3; ++c) acc[r][c] = 0.f;
  int kbase = w * 16;
#pragma unroll 4
  for (int i = 0; i < 16; ++i) {
    int k4 = kbase + i;
    const float* wr = wbase + (k4 * 4) * 3072;
    float w00 = wr[0],    w01 = wr[1],    w02 = wr[2];     // k = 4*k4+0
    float w10 = wr[3072], w11 = wr[3073], w12 = wr[3074];  // k = 4*k4+1
    float w20 = wr[6144], w21 = wr[6145], w22 = wr[6146];  // k = 4*k4+2
    float w30 = wr[9216], w31 = wr[9217], w32 = wr[9218];  // k = 4*k4+3
#pragma unroll
    for (int r = 0; r < 8; ++r) {
      float4 A = a_lds[r * 128 + k4];      // wave-uniform broadcast
      acc[r][0] += A.x * w00 + A.y * w10 + A.z * w20 + A.w * w30;
      acc[r][1] += A.x * w01 + A.y * w11 + A.z * w21 + A.w * w31;
      acc[r][2] += A.x * w02 + A.y * w12 + A.z * w22 + A.w * w32;
    }
  }
#pragma unroll
  for (int r = 0; r < 8; ++r)
#pragma unroll
    for (int c = 0; c < 3; ++c)
      part[((r * 3 + c) * 8 + w) * 64 + lane] = acc[r][c];
  __syncthreads();
  // combine: thread (w,lane) -> output row w, col p
  {
    int r = w;
    float s0 = 0.f, s1 = 0.f, s2 = 0.f;
#pragma unroll
    for (int ww = 0; ww < 8; ++ww) {
      s0 += part[((r * 3 + 0) * 8 + ww) * 64 + lane];
      s1 += part[((r * 3 + 1) * 8 + ww) * 64 + lane];
      s2 += part[((r * 3 + 2) * 8 + ww) * 64 + lane];
    }
    float b0 = bd3[p * 3], b1 = bd3[p * 3 + 1], b2 = bd3[p * 3 + 2];
    float y0 = tanhf(s0 + b0), y1 = tanhf(s1 + b1), y2 = tanhf(s2 + b2);
    int row = rt * 8 + r;
    Y4[row * 1024 + p] = make_float4(-2.f * y0, -2.f * y1, -2.f * y2,
                                     y0 * y0 + y1 * y1 + y2 * y2);
  }
}

// ---------------- KD: merged chamfer, packed f32x2 hot loop ----------------
// blocks 0..255: dir1 (sum_n min_m), blocks 256..511: dir2 partial mins.
// Pair of distances via __builtin_elementwise_fma on float2 (compiler may
// select v_pk_fma_f32): 3 fma-ops + 2 min per 2 pairs. FMA nesting order
// (z, then y, then x) matches the verified scalar loop -> identical results.
__global__ __launch_bounds__(256) void kD_chamfer(
    const float4* __restrict__ Y4, const float4* __restrict__ S4,
    float* __restrict__ mpart, float* __restrict__ out) {
  __shared__ float4 c_lds[1024];           // 16 KB inner cloud
  int t = threadIdx.x;
  if (blockIdx.x < 256) {
    // ---- dir1: resident my = (-2y, |y|^2); LDS = S (plain, |s|^2) ----
    int b = blockIdx.x >> 7, nt = blockIdx.x & 127;
    {
      const float4* src = S4 + b * 1024;
#pragma unroll
      for (int i = 0; i < 4; ++i) c_lds[i * 256 + t] = src[i * 256 + t];
    }
    float4 my0 = Y4[b * 65536 + nt * 512 + t];
    float4 my1 = Y4[b * 65536 + nt * 512 + 256 + t];
    f32x2 mx2 = {my0.x, my1.x};
    f32x2 my2 = {my0.y, my1.y};
    f32x2 mz2 = {my0.z, my1.z};
    __syncthreads();
    float mn0 = __builtin_inff(), mn1 = mn0;
#pragma unroll 8
    for (int m = 0; m < 1024; ++m) {
      float4 s = c_lds[m];                 // block-uniform broadcast
      f32x2 sx2 = {s.x, s.x}, sy2 = {s.y, s.y};
      f32x2 sz2 = {s.z, s.z}, sw2 = {s.w, s.w};
      f32x2 d = __builtin_elementwise_fma(sz2, mz2, sw2);
      d = __builtin_elementwise_fma(sy2, my2, d);
      d = __builtin_elementwise_fma(sx2, mx2, d);
      mn0 = fminf(mn0, d.x);
      mn1 = fminf(mn1, d.y);
    }
    float v = (mn0 + my0.w) + (mn1 + my1.w);
#pragma unroll
    for (int off = 32; off > 0; off >>= 1) v += __shfl_down(v, off);
    __shared__ float bsum[4];
    int lane = t & 63, w = t >> 6;
    if (lane == 0) bsum[w] = v;
    __syncthreads();
    if (t == 0) atomicAdd(out, bsum[0] + bsum[1] + bsum[2] + bsum[3]);
  } else {
    // ---- dir2: resident s (plain); LDS = Y' = (-2y, |y|^2) ----
    int blk = blockIdx.x - 256;            // 0..255
    int b   = blk >> 7;
    int mg  = (blk >> 6) & 1;
    int nch = blk & 63;
    {
      const float4* src = Y4 + b * 65536 + nch * 1024;
#pragma unroll
      for (int i = 0; i < 4; ++i) c_lds[i * 256 + t] = src[i * 256 + t];
    }
    float4 s0 = S4[b * 1024 + mg * 512 + t];
    float4 s1 = S4[b * 1024 + mg * 512 + 256 + t];
    f32x2 sx2 = {s0.x, s1.x};
    f32x2 sy2 = {s0.y, s1.y};
    f32x2 sz2 = {s0.z, s1.z};
    __syncthreads();
    float mn0 = __builtin_inff(), mn1 = mn0;
#pragma unroll 8
    for (int n = 0; n < 1024; ++n) {
      float4 y = c_lds[n];
      f32x2 yx2 = {y.x, y.x}, yy2 = {y.y, y.y};
      f32x2 yz2 = {y.z, y.z}, yw2 = {y.w, y.w};
      f32x2 d = __builtin_elementwise_fma(yz2, sz2, yw2);
      d = __builtin_elementwise_fma(yy2, sy2, d);
      d = __builtin_elementwise_fma(yx2, sx2, d);
      mn0 = fminf(mn0, d.x);
      mn1 = fminf(mn1, d.y);
    }
    int base = (nch * 2 + b) * 1024 + mg * 512;
    mpart[base + t]       = mn0 + s0.w;
    mpart[base + 256 + t] = mn1 + s1.w;
  }
}

// ---------------- KE: dir2 final reduce ----------------
__global__ __launch_bounds__(256) void kE_dir2_reduce(
    const float* __restrict__ mpart, float* __restrict__ out) {
  int gid = blockIdx.x * 256 + threadIdx.x;   // 0..2047
  int b = gid >> 10, m = gid & 1023;
  float v = __builtin_inff();
#pragma unroll 8
  for (int ch = 0; ch < 64; ++ch)
    v = fminf(v, mpart[(ch * 2 + b) * 1024 + m]);  // coalesced over m
#pragma unroll
  for (int off = 32; off > 0; off >>= 1) v += __shfl_down(v, off);
  __shared__ float bsum[4];
  int lane = threadIdx.x & 63, w = threadIdx.x >> 6;
  if (lane == 0) bsum[w] = v;
  __syncthreads();
  if (threadIdx.x == 0) atomicAdd(out, bsum[0] + bsum[1] + bsum[2] + bsum[3]);
}

extern "C" void kernel_launch(void* const* d_in, const int* in_sizes, int n_in,
                              void* d_out, int out_size, void* d_ws, size_t ws_size,
                              hipStream_t stream) {
  const float* x   = (const float*)d_in[0];
  const float* grd = (const float*)d_in[1];
  const float* We1 = (const float*)d_in[2];
  const float* be1 = (const float*)d_in[3];
  const float* We2 = (const float*)d_in[4];
  const float* be2 = (const float*)d_in[5];
  const float* We3 = (const float*)d_in[6];
  const float* be3 = (const float*)d_in[7];
  const float* Wd1 = (const float*)d_in[8];
  const float* bd1 = (const float*)d_in[9];
  const float* Wd2 = (const float*)d_in[10];
  const float* bd2 = (const float*)d_in[11];
  const float* Wd3 = (const float*)d_in[12];
  const float* bd3 = (const float*)d_in[13];
  float* ws = (float*)d_ws;
  float* out = (float*)d_out;

  float* gw     = ws + OFF_GW;
  float* h1part = ws + OFF_H1P;
  float* zw     = ws + OFF_ZW;
  float* S4     = ws + OFF_S4;
  float* Y4     = ws + OFF_Y4;
  float* mpart  = ws + OFF_MPART;

  hipLaunchKernelGGL(kA_init, dim3(112), dim3(256), 0, stream,
                     x, grd, Wd1, We1, gw, S4, h1part);
  hipLaunchKernelGGL(kB_enc, dim3(2), dim3(512), 0, stream,
                     h1part, be1, We2, be2, We3, be3, Wd1, bd1, zw, out);
  hipLaunchKernelGGL(kC_dec23_y4, dim3(256), dim3(512), 0, stream,
                     zw, gw, Wd2, bd2, Wd3, bd3, (float4*)Y4);
  hipLaunchKernelGGL(kD_chamfer, dim3(512), dim3(256), 0, stream,
                     (const float4*)Y4, (const float4*)S4, mpart, out);
  hipLaunchKernelGGL(kE_dir2_reduce, dim3(8), dim3(256), 0, stream,
                     mpart, out);
}

// Round 8
// 161.715 us; speedup vs baseline: 1.0424x; 1.0082x over previous
//
#include <hip/hip_runtime.h>

// Problem constants
#define NB 2        // batch
#define NPTS 1024   // points per cloud
#define NGEN 65536  // G * D_IN generated points per batch

typedef float f32x2 __attribute__((ext_vector_type(2)));

// ws layout (float offsets), all 16B-aligned where accessed as float4.
#define OFF_GW    0        // 8192
#define OFF_H1P   8192     // 24576 (24 k-chunks x 2 b x 512 j)
#define OFF_ZW    32768    // 256 (pad to 512)
#define OFF_S4    33280    // 8192
#define OFF_Y4    41472    // 524288
#define OFF_MPART 565760   // 131072
// total 696832 floats = 2.8 MB

// ---------------- KA: init + S4 pack + gw + enc1 (no transpose) ----------------
// blocks 0..63: gw + S4 pack; blocks 64..111: encoder L1 k-split partials,
// merged over batch (both b share each We1 load).
__global__ __launch_bounds__(256) void kA_init(
    const float* __restrict__ x, const float* __restrict__ grid,
    const float* __restrict__ Wd1, const float* __restrict__ We1,
    float* __restrict__ gw, float* __restrict__ S4,
    float* __restrict__ h1part) {
  if (blockIdx.x < 64) {
    int t = blockIdx.x * 256 + threadIdx.x;
    if (t < 8192) {
      int g = t >> 7, j = t & 127;
      float a = grid[g * 3 + 0] * Wd1[64 * 128 + j]
              + grid[g * 3 + 1] * Wd1[65 * 128 + j]
              + grid[g * 3 + 2] * Wd1[66 * 128 + j];
      gw[t] = a;
    } else if (t < 10240) {
      int p = t - 8192;
      const float* xp = x + p * 3;
      float s0 = xp[0], s1 = xp[1], s2 = xp[2];
      ((float4*)S4)[p] = make_float4(s0, s1, s2, s0 * s0 + s1 * s1 + s2 * s2);
    }
  } else {
    // enc1: 48 blocks = 24 kc x 2 jh; 256 threads each; both batches per block.
    int idx = blockIdx.x - 64;                        // 0..47
    int kc = idx % 24;
    int jh = idx / 24;                                // 0..1
    int j = jh * 256 + threadIdx.x;
    const float* xb0 = x + kc * 128;                  // uniform -> s_load
    const float* xb1 = x + 3072 + kc * 128;
    const float* W  = We1 + (kc * 128) * 512 + j;
    float acc0 = 0.f, acc1 = 0.f;
#pragma unroll 16
    for (int k = 0; k < 128; ++k) {
      float wv = W[k * 512];
      acc0 += xb0[k] * wv;
      acc1 += xb1[k] * wv;
    }
    h1part[kc * 1024 + j] = acc0;                     // b=0 partial
    h1part[kc * 1024 + 512 + j] = acc1;               // b=1 partial
  }
}

// ---------------- KB: encoder tail (h1->h2->z->zw), k-split (R2-verified) --------
// 2 blocks (one per batch) x 512 threads. Every phase splits K across q
// sub-chunks so all global loads issue concurrently; LDS partial-reduce.
// Also zeroes out[0].
__global__ __launch_bounds__(512) void kB_enc(
    const float* __restrict__ h1part, const float* __restrict__ be1,
    const float* __restrict__ We2, const float* __restrict__ be2,
    const float* __restrict__ We3, const float* __restrict__ be3,
    const float* __restrict__ Wd1, const float* __restrict__ bd1,
    float* __restrict__ zw, float* __restrict__ out) {
  __shared__ float h1l[512];
  __shared__ float h2p[512];
  __shared__ float h2l[128];
  __shared__ float zp[512];
  __shared__ float zl[64];
  __shared__ float wp[512];
  int b = blockIdx.x;
  int t = threadIdx.x;
  if (b == 0 && t == 0) out[0] = 0.f;
  // h1[k] = relu(be1[k] + sum_kc h1part[kc][b][k]); one k per thread.
  {
    float a = be1[t];
#pragma unroll
    for (int kc = 0; kc < 24; ++kc) a += h1part[kc * 1024 + b * 512 + t];
    h1l[t] = fmaxf(a, 0.f);
  }
  __syncthreads();
  // h2 partials: thread (q<4, j<128) does K-slice [128q,128q+128).
  {
    int q = t >> 7, j = t & 127;
    const float* W = We2 + (q * 128) * 128 + j;
    const float* h = h1l + q * 128;
    float a = 0.f;
#pragma unroll 16
    for (int k = 0; k < 128; ++k) a += h[k] * W[k * 128];
    h2p[t] = a;
  }
  __syncthreads();
  if (t < 128)
    h2l[t] = fmaxf(h2p[t] + h2p[128 + t] + h2p[256 + t] + h2p[384 + t]
                   + be2[t], 0.f);
  __syncthreads();
  // z partials: thread (q<8, j<64) does K-slice of 16.
  {
    int q = t >> 6, j = t & 63;
    float a = 0.f;
#pragma unroll
    for (int kk = 0; kk < 16; ++kk) {
      int k = q * 16 + kk;
      a += h2l[k] * We3[k * 64 + j];
    }
    zp[t] = a;
  }
  __syncthreads();
  if (t < 64) {
    float a = be3[t];
#pragma unroll
    for (int q = 0; q < 8; ++q) a += zp[q * 64 + t];
    zl[t] = fmaxf(a, 0.f);
  }
  __syncthreads();
  // zw partials: thread (q<4, j<128) does K-slice of 16 over Wd1 rows 0..63.
  {
    int q = t >> 7, j = t & 127;
    float a = 0.f;
#pragma unroll
    for (int kk = 0; kk < 16; ++kk) {
      int k = q * 16 + kk;
      a += zl[k] * Wd1[k * 128 + j];
    }
    wp[t] = a;
  }
  __syncthreads();
  if (t < 128)
    zw[b * 128 + t] = wp[t] + wp[128 + t] + wp[256 + t] + wp[384 + t]
                      + bd1[t];
}

// ---------------- KC: dec2 + dec3 + tanh + (-2y,|y|^2) pack ----------------
// 256 blocks = rt(16) x pg(16); 512 threads = 8 waves.
// Phase A: d1 = relu(zw+gw), stored [k][r] so phase B reads 2 b128 / k.
// Phase B: dec2 -> a_lds; packed f32x2 accumulators (4 pk_fma per k).
// Phase C: dec3 k-split reading Wd3 DIRECTLY (dwordx3 per k, 12 contiguous
// bytes/lane); bit-identical expression shape to the old Wt4 version.
__global__ __launch_bounds__(512) void kC_dec23_y4(
    const float* __restrict__ zw, const float* __restrict__ gw,
    const float* __restrict__ Wd2, const float* __restrict__ bd2,
    const float* __restrict__ Wd3, const float* __restrict__ bd3,
    float4* __restrict__ Y4) {
  __shared__ float4 a_lds[8 * 128];        // 8 rows x 512 k = 16 KB
  __shared__ float part[8 * 3 * 8 * 64];   // [r][c][w][lane] = 48 KB
  __shared__ float d1l[128 * 8];           // [k][r], 4 KB
  int rt = blockIdx.x >> 4;
  int pg = blockIdx.x & 15;
  int t = threadIdx.x;
  // Phase A: d1 for rows rt*8..rt*8+7, stored d1l[kk*8 + r]
#pragma unroll
  for (int i = 0; i < 2; ++i) {
    int idx2 = i * 512 + t;
    int r = idx2 >> 7, kk = idx2 & 127;
    int row = rt * 8 + r, b = row >> 6, g = row & 63;
    d1l[kk * 8 + r] = fmaxf(zw[b * 128 + kk] + gw[g * 128 + kk], 0.f);
  }
  __syncthreads();
  // Phase B: dec2 -> a_lds rows (thread = output column j); packed pairs.
  {
    float* a_f = (float*)a_lds;
    int j = t;
    float bj = bd2[j];
    f32x2 acc01 = {bj, bj}, acc23 = {bj, bj};
    f32x2 acc45 = {bj, bj}, acc67 = {bj, bj};
#pragma unroll 8
    for (int k = 0; k < 128; ++k) {
      float wv = Wd2[k * 512 + j];
      f32x2 wv2 = {wv, wv};
      float4 lo = *(const float4*)(d1l + k * 8);      // rows 0..3 (broadcast)
      float4 hi = *(const float4*)(d1l + k * 8 + 4);  // rows 4..7
      f32x2 d01 = {lo.x, lo.y}, d23 = {lo.z, lo.w};
      f32x2 d45 = {hi.x, hi.y}, d67 = {hi.z, hi.w};
      acc01 = __builtin_elementwise_fma(d01, wv2, acc01);
      acc23 = __builtin_elementwise_fma(d23, wv2, acc23);
      acc45 = __builtin_elementwise_fma(d45, wv2, acc45);
      acc67 = __builtin_elementwise_fma(d67, wv2, acc67);
    }
    a_f[0 * 512 + j] = fmaxf(acc01.x, 0.f);
    a_f[1 * 512 + j] = fmaxf(acc01.y, 0.f);
    a_f[2 * 512 + j] = fmaxf(acc23.x, 0.f);
    a_f[3 * 512 + j] = fmaxf(acc23.y, 0.f);
    a_f[4 * 512 + j] = fmaxf(acc45.x, 0.f);
    a_f[5 * 512 + j] = fmaxf(acc45.y, 0.f);
    a_f[6 * 512 + j] = fmaxf(acc67.x, 0.f);
    a_f[7 * 512 + j] = fmaxf(acc67.y, 0.f);
  }
  __syncthreads();
  // Phase C: dec3 (wave w owns k4 range [16w,16w+16) for ALL 8 rows)
  int lane = t & 63, w = t >> 6;           // w = 0..7
  int p = pg * 64 + lane;
  const float* wbase = Wd3 + 3 * p;        // row k at wbase + k*3072
  float acc[8][3];
#pragma unroll
  for (int r = 0; r < 8; ++r)
#pragma unroll
    for (int c = 0; c < 3; ++c) acc[r][c] = 0.f;
  int kbase = w * 16;
#pragma unroll 4
  for (int i = 0; i < 16; ++i) {
    int k4 = kbase + i;
    const float* wr = wbase + (k4 * 4) * 3072;
    float w00 = wr[0],    w01 = wr[1],    w02 = wr[2];     // k = 4*k4+0
    float w10 = wr[3072], w11 = wr[3073], w12 = wr[3074];  // k = 4*k4+1
    float w20 = wr[6144], w21 = wr[6145], w22 = wr[6146];  // k = 4*k4+2
    float w30 = wr[9216], w31 = wr[9217], w32 = wr[9218];  // k = 4*k4+3
#pragma unroll
    for (int r = 0; r < 8; ++r) {
      float4 A = a_lds[r * 128 + k4];      // wave-uniform broadcast
      acc[r][0] += A.x * w00 + A.y * w10 + A.z * w20 + A.w * w30;
      acc[r][1] += A.x * w01 + A.y * w11 + A.z * w21 + A.w * w31;
      acc[r][2] += A.x * w02 + A.y * w12 + A.z * w22 + A.w * w32;
    }
  }
#pragma unroll
  for (int r = 0; r < 8; ++r)
#pragma unroll
    for (int c = 0; c < 3; ++c)
      part[((r * 3 + c) * 8 + w) * 64 + lane] = acc[r][c];
  __syncthreads();
  // combine: thread (w,lane) -> output row w, col p
  {
    int r = w;
    float s0 = 0.f, s1 = 0.f, s2 = 0.f;
#pragma unroll
    for (int ww = 0; ww < 8; ++ww) {
      s0 += part[((r * 3 + 0) * 8 + ww) * 64 + lane];
      s1 += part[((r * 3 + 1) * 8 + ww) * 64 + lane];
      s2 += part[((r * 3 + 2) * 8 + ww) * 64 + lane];
    }
    float b0 = bd3[p * 3], b1 = bd3[p * 3 + 1], b2 = bd3[p * 3 + 2];
    float y0 = tanhf(s0 + b0), y1 = tanhf(s1 + b1), y2 = tanhf(s2 + b2);
    int row = rt * 8 + r;
    Y4[row * 1024 + p] = make_float4(-2.f * y0, -2.f * y1, -2.f * y2,
                                     y0 * y0 + y1 * y1 + y2 * y2);
  }
}

// ---------------- KD: merged chamfer, packed f32x2 fma+min hot loop ----------------
// blocks 0..255: dir1 (sum_n min_m), blocks 256..511: dir2 partial mins.
// Pair of distances via __builtin_elementwise_fma / _min on float2 (compiler
// may select v_pk_fma_f32 / v_pk_min_f32): 3 fma + 1 min per 2 pairs.
// FMA nesting order (z, then y, then x) matches the verified scalar loop;
// minnum == fminf on finite values -> identical results.
__global__ __launch_bounds__(256) void kD_chamfer(
    const float4* __restrict__ Y4, const float4* __restrict__ S4,
    float* __restrict__ mpart, float* __restrict__ out) {
  __shared__ float4 c_lds[1024];           // 16 KB inner cloud
  int t = threadIdx.x;
  if (blockIdx.x < 256) {
    // ---- dir1: resident my = (-2y, |y|^2); LDS = S (plain, |s|^2) ----
    int b = blockIdx.x >> 7, nt = blockIdx.x & 127;
    {
      const float4* src = S4 + b * 1024;
#pragma unroll
      for (int i = 0; i < 4; ++i) c_lds[i * 256 + t] = src[i * 256 + t];
    }
    float4 my0 = Y4[b * 65536 + nt * 512 + t];
    float4 my1 = Y4[b * 65536 + nt * 512 + 256 + t];
    f32x2 mx2 = {my0.x, my1.x};
    f32x2 my2 = {my0.y, my1.y};
    f32x2 mz2 = {my0.z, my1.z};
    __syncthreads();
    f32x2 mn2 = {__builtin_inff(), __builtin_inff()};
#pragma unroll 8
    for (int m = 0; m < 1024; ++m) {
      float4 s = c_lds[m];                 // block-uniform broadcast
      f32x2 sx2 = {s.x, s.x}, sy2 = {s.y, s.y};
      f32x2 sz2 = {s.z, s.z}, sw2 = {s.w, s.w};
      f32x2 d = __builtin_elementwise_fma(sz2, mz2, sw2);
      d = __builtin_elementwise_fma(sy2, my2, d);
      d = __builtin_elementwise_fma(sx2, mx2, d);
      mn2 = __builtin_elementwise_min(mn2, d);
    }
    float v = (mn2.x + my0.w) + (mn2.y + my1.w);
#pragma unroll
    for (int off = 32; off > 0; off >>= 1) v += __shfl_down(v, off);
    __shared__ float bsum[4];
    int lane = t & 63, w = t >> 6;
    if (lane == 0) bsum[w] = v;
    __syncthreads();
    if (t == 0) atomicAdd(out, bsum[0] + bsum[1] + bsum[2] + bsum[3]);
  } else {
    // ---- dir2: resident s (plain); LDS = Y' = (-2y, |y|^2) ----
    int blk = blockIdx.x - 256;            // 0..255
    int b   = blk >> 7;
    int mg  = (blk >> 6) & 1;
    int nch = blk & 63;
    {
      const float4* src = Y4 + b * 65536 + nch * 1024;
#pragma unroll
      for (int i = 0; i < 4; ++i) c_lds[i * 256 + t] = src[i * 256 + t];
    }
    float4 s0 = S4[b * 1024 + mg * 512 + t];
    float4 s1 = S4[b * 1024 + mg * 512 + 256 + t];
    f32x2 sx2 = {s0.x, s1.x};
    f32x2 sy2 = {s0.y, s1.y};
    f32x2 sz2 = {s0.z, s1.z};
    __syncthreads();
    f32x2 mn2 = {__builtin_inff(), __builtin_inff()};
#pragma unroll 8
    for (int n = 0; n < 1024; ++n) {
      float4 y = c_lds[n];
      f32x2 yx2 = {y.x, y.x}, yy2 = {y.y, y.y};
      f32x2 yz2 = {y.z, y.z}, yw2 = {y.w, y.w};
      f32x2 d = __builtin_elementwise_fma(yz2, sz2, yw2);
      d = __builtin_elementwise_fma(yy2, sy2, d);
      d = __builtin_elementwise_fma(yx2, sx2, d);
      mn2 = __builtin_elementwise_min(mn2, d);
    }
    int base = (nch * 2 + b) * 1024 + mg * 512;
    mpart[base + t]       = mn2.x + s0.w;
    mpart[base + 256 + t] = mn2.y + s1.w;
  }
}

// ---------------- KE: dir2 final reduce ----------------
__global__ __launch_bounds__(256) void kE_dir2_reduce(
    const float* __restrict__ mpart, float* __restrict__ out) {
  int gid = blockIdx.x * 256 + threadIdx.x;   // 0..2047
  int b = gid >> 10, m = gid & 1023;
  float v = __builtin_inff();
#pragma unroll 8
  for (int ch = 0; ch < 64; ++ch)
    v = fminf(v, mpart[(ch * 2 + b) * 1024 + m]);  // coalesced over m
#pragma unroll
  for (int off = 32; off > 0; off >>= 1) v += __shfl_down(v, off);
  __shared__ float bsum[4];
  int lane = threadIdx.x & 63, w = threadIdx.x >> 6;
  if (lane == 0) bsum[w] = v;
  __syncthreads();
  if (threadIdx.x == 0) atomicAdd(out, bsum[0] + bsum[1] + bsum[2] + bsum[3]);
}

extern "C" void kernel_launch(void* const* d_in, const int* in_sizes, int n_in,
                              void* d_out, int out_size, void* d_ws, size_t ws_size,
                              hipStream_t stream) {
  const float* x   = (const float*)d_in[0];
  const float* grd = (const float*)d_in[1];
  const float* We1 = (const float*)d_in[2];
  const float* be1 = (const float*)d_in[3];
  const float* We2 = (const float*)d_in[4];
  const float* be2 = (const float*)d_in[5];
  const float* We3 = (const float*)d_in[6];
  const float* be3 = (const float*)d_in[7];
  const float* Wd1 = (const float*)d_in[8];
  const float* bd1 = (const float*)d_in[9];
  const float* Wd2 = (const float*)d_in[10];
  const float* bd2 = (const float*)d_in[11];
  const float* Wd3 = (const float*)d_in[12];
  const float* bd3 = (const float*)d_in[13];
  float* ws = (float*)d_ws;
  float* out = (float*)d_out;

  float* gw     = ws + OFF_GW;
  float* h1part = ws + OFF_H1P;
  float* zw     = ws + OFF_ZW;
  float* S4     = ws + OFF_S4;
  float* Y4     = ws + OFF_Y4;
  float* mpart  = ws + OFF_MPART;

  hipLaunchKernelGGL(kA_init, dim3(112), dim3(256), 0, stream,
                     x, grd, Wd1, We1, gw, S4, h1part);
  hipLaunchKernelGGL(kB_enc, dim3(2), dim3(512), 0, stream,
                     h1part, be1, We2, be2, We3, be3, Wd1, bd1, zw, out);
  hipLaunchKernelGGL(kC_dec23_y4, dim3(256), dim3(512), 0, stream,
                     zw, gw, Wd2, bd2, Wd3, bd3, (float4*)Y4);
  hipLaunchKernelGGL(kD_chamfer, dim3(512), dim3(256), 0, stream,
                     (const float4*)Y4, (const float4*)S4, mpart, out);
  hipLaunchKernelGGL(kE_dir2_reduce, dim3(8), dim3(256), 0, stream,
                     mpart, out);
}

// Round 9
// 148.885 us; speedup vs baseline: 1.1323x; 1.0862x over previous
//
#include <hip/hip_runtime.h>

// Problem constants
#define NB 2        // batch
#define NPTS 1024   // points per cloud
#define NGEN 65536  // G * D_IN generated points per batch

typedef float f32x2 __attribute__((ext_vector_type(2)));

// ws layout (float offsets), all 16B-aligned where accessed as float4.
#define OFF_GW    0        // 8192
#define OFF_H1P   8192     // 49152 (48 k-chunks x 2 b x 512 j)
#define OFF_ZW    57344    // 256 (pad to 512)
#define OFF_S4    57856    // 8192
#define OFF_Y4    66048    // 524288
#define OFF_MPART 590336   // 131072
// total 721408 floats = 2.9 MB

// ---------------- KA: init + S4 pack + gw + enc1 (spread k-split) ----------------
// blocks 0..63: gw + S4 pack; blocks 64..159: encoder L1 partials,
// 48 K-chunks of 64 x 2 j-halves; both batches share each We1 load.
__global__ __launch_bounds__(256) void kA_init(
    const float* __restrict__ x, const float* __restrict__ grid,
    const float* __restrict__ Wd1, const float* __restrict__ We1,
    float* __restrict__ gw, float* __restrict__ S4,
    float* __restrict__ h1part) {
  if (blockIdx.x < 64) {
    int t = blockIdx.x * 256 + threadIdx.x;
    if (t < 8192) {
      int g = t >> 7, j = t & 127;
      float a = grid[g * 3 + 0] * Wd1[64 * 128 + j]
              + grid[g * 3 + 1] * Wd1[65 * 128 + j]
              + grid[g * 3 + 2] * Wd1[66 * 128 + j];
      gw[t] = a;
    } else if (t < 10240) {
      int p = t - 8192;
      const float* xp = x + p * 3;
      float s0 = xp[0], s1 = xp[1], s2 = xp[2];
      ((float4*)S4)[p] = make_float4(s0, s1, s2, s0 * s0 + s1 * s1 + s2 * s2);
    }
  } else {
    // enc1: 96 blocks = 48 kc x 2 jh; 256 threads each; both batches per block.
    int idx = blockIdx.x - 64;                        // 0..95
    int kc = idx % 48;
    int jh = idx / 48;                                // 0..1
    int j = jh * 256 + threadIdx.x;
    const float* xb0 = x + kc * 64;                   // uniform -> s_load
    const float* xb1 = x + 3072 + kc * 64;
    const float* W  = We1 + (kc * 64) * 512 + j;
    float acc0 = 0.f, acc1 = 0.f;
#pragma unroll 16
    for (int k = 0; k < 64; ++k) {
      float wv = W[k * 512];
      acc0 += xb0[k] * wv;
      acc1 += xb1[k] * wv;
    }
    h1part[kc * 1024 + j] = acc0;                     // b=0 partial
    h1part[kc * 1024 + 512 + j] = acc1;               // b=1 partial
  }
}

// ---------------- KB: encoder tail (h1->h2->z->zw), k-split (R2-verified) --------
// 2 blocks (one per batch) x 512 threads. Every phase splits K across q
// sub-chunks so all global loads issue concurrently; LDS partial-reduce.
// Also zeroes out[0].
__global__ __launch_bounds__(512) void kB_enc(
    const float* __restrict__ h1part, const float* __restrict__ be1,
    const float* __restrict__ We2, const float* __restrict__ be2,
    const float* __restrict__ We3, const float* __restrict__ be3,
    const float* __restrict__ Wd1, const float* __restrict__ bd1,
    float* __restrict__ zw, float* __restrict__ out) {
  __shared__ float h1l[512];
  __shared__ float h2p[512];
  __shared__ float h2l[128];
  __shared__ float zp[512];
  __shared__ float zl[64];
  __shared__ float wp[512];
  int b = blockIdx.x;
  int t = threadIdx.x;
  if (b == 0 && t == 0) out[0] = 0.f;
  // h1[k] = relu(be1[k] + sum_kc h1part[kc][b][k]); one k per thread.
  {
    float a = be1[t];
#pragma unroll 16
    for (int kc = 0; kc < 48; ++kc) a += h1part[kc * 1024 + b * 512 + t];
    h1l[t] = fmaxf(a, 0.f);
  }
  __syncthreads();
  // h2 partials: thread (q<4, j<128) does K-slice [128q,128q+128).
  {
    int q = t >> 7, j = t & 127;
    const float* W = We2 + (q * 128) * 128 + j;
    const float* h = h1l + q * 128;
    float a = 0.f;
#pragma unroll 16
    for (int k = 0; k < 128; ++k) a += h[k] * W[k * 128];
    h2p[t] = a;
  }
  __syncthreads();
  if (t < 128)
    h2l[t] = fmaxf(h2p[t] + h2p[128 + t] + h2p[256 + t] + h2p[384 + t]
                   + be2[t], 0.f);
  __syncthreads();
  // z partials: thread (q<8, j<64) does K-slice of 16.
  {
    int q = t >> 6, j = t & 63;
    float a = 0.f;
#pragma unroll
    for (int kk = 0; kk < 16; ++kk) {
      int k = q * 16 + kk;
      a += h2l[k] * We3[k * 64 + j];
    }
    zp[t] = a;
  }
  __syncthreads();
  if (t < 64) {
    float a = be3[t];
#pragma unroll
    for (int q = 0; q < 8; ++q) a += zp[q * 64 + t];
    zl[t] = fmaxf(a, 0.f);
  }
  __syncthreads();
  // zw partials: thread (q<4, j<128) does K-slice of 16 over Wd1 rows 0..63.
  {
    int q = t >> 7, j = t & 127;
    float a = 0.f;
#pragma unroll
    for (int kk = 0; kk < 16; ++kk) {
      int k = q * 16 + kk;
      a += zl[k] * Wd1[k * 128 + j];
    }
    wp[t] = a;
  }
  __syncthreads();
  if (t < 128)
    zw[b * 128 + t] = wp[t] + wp[128 + t] + wp[256 + t] + wp[384 + t]
                      + bd1[t];
}

// ---------------- KC: dec2 + dec3 + tanh + (-2y,|y|^2) pack ----------------
// 256 blocks = rt(16) x pg(16); 512 threads = 8 waves.
// Phase A: d1 = relu(zw+gw), stored [k][r] so phase B reads 2 b128 / k.
// Phase B: dec2 -> a_lds; packed f32x2 accumulators (4 pk_fma per k).
// Phase C: dec3 k-split reading Wd3 DIRECTLY (dwordx3 per k, 12 contiguous
// bytes/lane); bit-identical expression shape to the old Wt4 version.
__global__ __launch_bounds__(512) void kC_dec23_y4(
    const float* __restrict__ zw, const float* __restrict__ gw,
    const float* __restrict__ Wd2, const float* __restrict__ bd2,
    const float* __restrict__ Wd3, const float* __restrict__ bd3,
    float4* __restrict__ Y4) {
  __shared__ float4 a_lds[8 * 128];        // 8 rows x 512 k = 16 KB
  __shared__ float part[8 * 3 * 8 * 64];   // [r][c][w][lane] = 48 KB
  __shared__ float d1l[128 * 8];           // [k][r], 4 KB
  int rt = blockIdx.x >> 4;
  int pg = blockIdx.x & 15;
  int t = threadIdx.x;
  // Phase A: d1 for rows rt*8..rt*8+7, stored d1l[kk*8 + r]
#pragma unroll
  for (int i = 0; i < 2; ++i) {
    int idx2 = i * 512 + t;
    int r = idx2 >> 7, kk = idx2 & 127;
    int row = rt * 8 + r, b = row >> 6, g = row & 63;
    d1l[kk * 8 + r] = fmaxf(zw[b * 128 + kk] + gw[g * 128 + kk], 0.f);
  }
  __syncthreads();
  // Phase B: dec2 -> a_lds rows (thread = output column j); packed pairs.
  {
    float* a_f = (float*)a_lds;
    int j = t;
    float bj = bd2[j];
    f32x2 acc01 = {bj, bj}, acc23 = {bj, bj};
    f32x2 acc45 = {bj, bj}, acc67 = {bj, bj};
#pragma unroll 8
    for (int k = 0; k < 128; ++k) {
      float wv = Wd2[k * 512 + j];
      f32x2 wv2 = {wv, wv};
      float4 lo = *(const float4*)(d1l + k * 8);      // rows 0..3 (broadcast)
      float4 hi = *(const float4*)(d1l + k * 8 + 4);  // rows 4..7
      f32x2 d01 = {lo.x, lo.y}, d23 = {lo.z, lo.w};
      f32x2 d45 = {hi.x, hi.y}, d67 = {hi.z, hi.w};
      acc01 = __builtin_elementwise_fma(d01, wv2, acc01);
      acc23 = __builtin_elementwise_fma(d23, wv2, acc23);
      acc45 = __builtin_elementwise_fma(d45, wv2, acc45);
      acc67 = __builtin_elementwise_fma(d67, wv2, acc67);
    }
    a_f[0 * 512 + j] = fmaxf(acc01.x, 0.f);
    a_f[1 * 512 + j] = fmaxf(acc01.y, 0.f);
    a_f[2 * 512 + j] = fmaxf(acc23.x, 0.f);
    a_f[3 * 512 + j] = fmaxf(acc23.y, 0.f);
    a_f[4 * 512 + j] = fmaxf(acc45.x, 0.f);
    a_f[5 * 512 + j] = fmaxf(acc45.y, 0.f);
    a_f[6 * 512 + j] = fmaxf(acc67.x, 0.f);
    a_f[7 * 512 + j] = fmaxf(acc67.y, 0.f);
  }
  __syncthreads();
  // Phase C: dec3 (wave w owns k4 range [16w,16w+16) for ALL 8 rows)
  int lane = t & 63, w = t >> 6;           // w = 0..7
  int p = pg * 64 + lane;
  const float* wbase = Wd3 + 3 * p;        // row k at wbase + k*3072
  float acc[8][3];
#pragma unroll
  for (int r = 0; r < 8; ++r)
#pragma unroll
    for (int c = 0; c < 3; ++c) acc[r][c] = 0.f;
  int kbase = w * 16;
#pragma unroll 4
  for (int i = 0; i < 16; ++i) {
    int k4 = kbase + i;
    const float* wr = wbase + (k4 * 4) * 3072;
    float w00 = wr[0],    w01 = wr[1],    w02 = wr[2];     // k = 4*k4+0
    float w10 = wr[3072], w11 = wr[3073], w12 = wr[3074];  // k = 4*k4+1
    float w20 = wr[6144], w21 = wr[6145], w22 = wr[6146];  // k = 4*k4+2
    float w30 = wr[9216], w31 = wr[9217], w32 = wr[9218];  // k = 4*k4+3
#pragma unroll
    for (int r = 0; r < 8; ++r) {
      float4 A = a_lds[r * 128 + k4];      // wave-uniform broadcast
      acc[r][0] += A.x * w00 + A.y * w10 + A.z * w20 + A.w * w30;
      acc[r][1] += A.x * w01 + A.y * w11 + A.z * w21 + A.w * w31;
      acc[r][2] += A.x * w02 + A.y * w12 + A.z * w22 + A.w * w32;
    }
  }
#pragma unroll
  for (int r = 0; r < 8; ++r)
#pragma unroll
    for (int c = 0; c < 3; ++c)
      part[((r * 3 + c) * 8 + w) * 64 + lane] = acc[r][c];
  __syncthreads();
  // combine: thread (w,lane) -> output row w, col p
  {
    int r = w;
    float s0 = 0.f, s1 = 0.f, s2 = 0.f;
#pragma unroll
    for (int ww = 0; ww < 8; ++ww) {
      s0 += part[((r * 3 + 0) * 8 + ww) * 64 + lane];
      s1 += part[((r * 3 + 1) * 8 + ww) * 64 + lane];
      s2 += part[((r * 3 + 2) * 8 + ww) * 64 + lane];
    }
    float b0 = bd3[p * 3], b1 = bd3[p * 3 + 1], b2 = bd3[p * 3 + 2];
    float y0 = tanhf(s0 + b0), y1 = tanhf(s1 + b1), y2 = tanhf(s2 + b2);
    int row = rt * 8 + r;
    Y4[row * 1024 + p] = make_float4(-2.f * y0, -2.f * y1, -2.f * y2,
                                     y0 * y0 + y1 * y1 + y2 * y2);
  }
}

// ---------------- KD: merged chamfer, packed fma + min3-tree hot loop ----------------
// blocks 0..255: dir1 (sum_n min_m), blocks 256..511: dir2 partial mins.
// 2 LDS points per step; fold mins as min(min(mn,da),db) so clang fuses the
// scalarized chain to v_min3_f32 (1 slot/pair vs 2). Min over the same finite
// multiset in any order is identical; FMA nesting (z,y,x) unchanged.
__global__ __launch_bounds__(256) void kD_chamfer(
    const float4* __restrict__ Y4, const float4* __restrict__ S4,
    float* __restrict__ mpart, float* __restrict__ out) {
  __shared__ float4 c_lds[1024];           // 16 KB inner cloud
  int t = threadIdx.x;
  if (blockIdx.x < 256) {
    // ---- dir1: resident my = (-2y, |y|^2); LDS = S (plain, |s|^2) ----
    int b = blockIdx.x >> 7, nt = blockIdx.x & 127;
    {
      const float4* src = S4 + b * 1024;
#pragma unroll
      for (int i = 0; i < 4; ++i) c_lds[i * 256 + t] = src[i * 256 + t];
    }
    float4 my0 = Y4[b * 65536 + nt * 512 + t];
    float4 my1 = Y4[b * 65536 + nt * 512 + 256 + t];
    f32x2 mx2 = {my0.x, my1.x};
    f32x2 my2 = {my0.y, my1.y};
    f32x2 mz2 = {my0.z, my1.z};
    __syncthreads();
    f32x2 mn2 = {__builtin_inff(), __builtin_inff()};
#pragma unroll 4
    for (int m = 0; m < 1024; m += 2) {
      float4 sa = c_lds[m];                // block-uniform broadcast
      float4 sb = c_lds[m + 1];
      f32x2 da, db;
      {
        f32x2 sx2 = {sa.x, sa.x}, sy2 = {sa.y, sa.y};
        f32x2 sz2 = {sa.z, sa.z}, sw2 = {sa.w, sa.w};
        da = __builtin_elementwise_fma(sz2, mz2, sw2);
        da = __builtin_elementwise_fma(sy2, my2, da);
        da = __builtin_elementwise_fma(sx2, mx2, da);
      }
      {
        f32x2 sx2 = {sb.x, sb.x}, sy2 = {sb.y, sb.y};
        f32x2 sz2 = {sb.z, sb.z}, sw2 = {sb.w, sb.w};
        db = __builtin_elementwise_fma(sz2, mz2, sw2);
        db = __builtin_elementwise_fma(sy2, my2, db);
        db = __builtin_elementwise_fma(sx2, mx2, db);
      }
      mn2 = __builtin_elementwise_min(__builtin_elementwise_min(mn2, da), db);
    }
    float v = (mn2.x + my0.w) + (mn2.y + my1.w);
#pragma unroll
    for (int off = 32; off > 0; off >>= 1) v += __shfl_down(v, off);
    __shared__ float bsum[4];
    int lane = t & 63, w = t >> 6;
    if (lane == 0) bsum[w] = v;
    __syncthreads();
    if (t == 0) atomicAdd(out, bsum[0] + bsum[1] + bsum[2] + bsum[3]);
  } else {
    // ---- dir2: resident s (plain); LDS = Y' = (-2y, |y|^2) ----
    int blk = blockIdx.x - 256;            // 0..255
    int b   = blk >> 7;
    int mg  = (blk >> 6) & 1;
    int nch = blk & 63;
    {
      const float4* src = Y4 + b * 65536 + nch * 1024;
#pragma unroll
      for (int i = 0; i < 4; ++i) c_lds[i * 256 + t] = src[i * 256 + t];
    }
    float4 s0 = S4[b * 1024 + mg * 512 + t];
    float4 s1 = S4[b * 1024 + mg * 512 + 256 + t];
    f32x2 sx2 = {s0.x, s1.x};
    f32x2 sy2 = {s0.y, s1.y};
    f32x2 sz2 = {s0.z, s1.z};
    __syncthreads();
    f32x2 mn2 = {__builtin_inff(), __builtin_inff()};
#pragma unroll 4
    for (int n = 0; n < 1024; n += 2) {
      float4 ya = c_lds[n];
      float4 yb = c_lds[n + 1];
      f32x2 da, db;
      {
        f32x2 yx2 = {ya.x, ya.x}, yy2 = {ya.y, ya.y};
        f32x2 yz2 = {ya.z, ya.z}, yw2 = {ya.w, ya.w};
        da = __builtin_elementwise_fma(yz2, sz2, yw2);
        da = __builtin_elementwise_fma(yy2, sy2, da);
        da = __builtin_elementwise_fma(yx2, sx2, da);
      }
      {
        f32x2 yx2 = {yb.x, yb.x}, yy2 = {yb.y, yb.y};
        f32x2 yz2 = {yb.z, yb.z}, yw2 = {yb.w, yb.w};
        db = __builtin_elementwise_fma(yz2, sz2, yw2);
        db = __builtin_elementwise_fma(yy2, sy2, db);
        db = __builtin_elementwise_fma(yx2, sx2, db);
      }
      mn2 = __builtin_elementwise_min(__builtin_elementwise_min(mn2, da), db);
    }
    int base = (nch * 2 + b) * 1024 + mg * 512;
    mpart[base + t]       = mn2.x + s0.w;
    mpart[base + 256 + t] = mn2.y + s1.w;
  }
}

// ---------------- KE: dir2 final reduce (min3-tree) ----------------
__global__ __launch_bounds__(256) void kE_dir2_reduce(
    const float* __restrict__ mpart, float* __restrict__ out) {
  int gid = blockIdx.x * 256 + threadIdx.x;   // 0..2047
  int b = gid >> 10, m = gid & 1023;
  float v = __builtin_inff();
#pragma unroll 8
  for (int ch = 0; ch < 64; ch += 2) {
    float a = mpart[(ch * 2 + b) * 1024 + m];        // coalesced over m
    float c = mpart[((ch + 1) * 2 + b) * 1024 + m];
    v = fminf(fminf(v, a), c);                       // -> v_min3_f32
  }
#pragma unroll
  for (int off = 32; off > 0; off >>= 1) v += __shfl_down(v, off);
  __shared__ float bsum[4];
  int lane = threadIdx.x & 63, w = threadIdx.x >> 6;
  if (lane == 0) bsum[w] = v;
  __syncthreads();
  if (threadIdx.x == 0) atomicAdd(out, bsum[0] + bsum[1] + bsum[2] + bsum[3]);
}

extern "C" void kernel_launch(void* const* d_in, const int* in_sizes, int n_in,
                              void* d_out, int out_size, void* d_ws, size_t ws_size,
                              hipStream_t stream) {
  const float* x   = (const float*)d_in[0];
  const float* grd = (const float*)d_in[1];
  const float* We1 = (const float*)d_in[2];
  const float* be1 = (const float*)d_in[3];
  const float* We2 = (const float*)d_in[4];
  const float* be2 = (const float*)d_in[5];
  const float* We3 = (const float*)d_in[6];
  const float* be3 = (const float*)d_in[7];
  const float* Wd1 = (const float*)d_in[8];
  const float* bd1 = (const float*)d_in[9];
  const float* Wd2 = (const float*)d_in[10];
  const float* bd2 = (const float*)d_in[11];
  const float* Wd3 = (const float*)d_in[12];
  const float* bd3 = (const float*)d_in[13];
  float* ws = (float*)d_ws;
  float* out = (float*)d_out;

  float* gw     = ws + OFF_GW;
  float* h1part = ws + OFF_H1P;
  float* zw     = ws + OFF_ZW;
  float* S4     = ws + OFF_S4;
  float* Y4     = ws + OFF_Y4;
  float* mpart  = ws + OFF_MPART;

  hipLaunchKernelGGL(kA_init, dim3(160), dim3(256), 0, stream,
                     x, grd, Wd1, We1, gw, S4, h1part);
  hipLaunchKernelGGL(kB_enc, dim3(2), dim3(512), 0, stream,
                     h1part, be1, We2, be2, We3, be3, Wd1, bd1, zw, out);
  hipLaunchKernelGGL(kC_dec23_y4, dim3(256), dim3(512), 0, stream,
                     zw, gw, Wd2, bd2, Wd3, bd3, (float4*)Y4);
  hipLaunchKernelGGL(kD_chamfer, dim3(512), dim3(256), 0, stream,
                     (const float4*)Y4, (const float4*)S4, mpart, out);
  hipLaunchKernelGGL(kE_dir2_reduce, dim3(8), dim3(256), 0, stream,
                     mpart, out);
}